// Round 13
// baseline (838.245 us; speedup 1.0000x reference)
//
#include <hip/hip_runtime.h>
#include <math.h>

#define HID 128

__device__ __forceinline__ float gelu_f(float x){
  return 0.5f*x*(1.0f+erff(x*0.70710678118654752440f));
}

// ---------- combined-weight precompute ----------
__global__ void mkw(const float* __restrict__ Wkqv, const float* __restrict__ bkqv,
                    const float* __restrict__ arel, const float* __restrict__ mrel,
                    const float* __restrict__ prel,
                    float* __restrict__ Wc, float* __restrict__ bc) {
  int L = blockIdx.x >> 10;
  int j = blockIdx.x & 1023;
  int t = threadIdx.x;
  int type = (j < 640) ? 0 : 1;
  int jj = (j < 640) ? j : j - 640;
  const float* W    = Wkqv + ((size_t)L*2 + type)*49152;
  const float* bsrc = bkqv + ((size_t)L*2 + type)*384;
  int stride = type ? 384 : 640;
  float* Wdst = Wc + (size_t)L*(640+384)*128 + (type ? (size_t)640*128 : 0);
  float* bdst = bc + (size_t)L*1024 + (type ? 640 : 0);
  float val, bval;
  if (jj < 128) {
    val  = W[(size_t)t*384 + 128 + jj];
    bval = bsrc[128 + jj];
  } else {
    int u = jj - 128;
    int et = type ? 2 : (u >> 8);
    int r = u & 255;
    int h = r >> 6, wofs = r & 63;
    const float* rel; int coloff; float scl;
    if (wofs < 32) {
      rel = arel + ((size_t)L*3 + et)*4096 + (size_t)h*32*32 + wofs;
      coloff = h*32;
      scl = prel[((size_t)L*3 + et)*4 + h] * 0.17677669529663688f * 1.4426950408889634f;
    } else {
      rel = mrel + ((size_t)L*3 + et)*4096 + (size_t)h*32*32 + (wofs - 32);
      coloff = 256 + h*32;
      scl = 1.0f;
    }
    float a = 0.f, bb = 0.f;
    for (int d = 0; d < 32; d++) {
      float rv = rel[(size_t)d*32];
      a  += W[(size_t)t*384 + coloff + d] * rv;
      bb += bsrc[coloff + d] * rv;
    }
    val = a * scl; bval = bb * scl;
  }
  Wdst[(size_t)t*stride + jj] = val;
  if (t == 0) bdst[jj] = bval;
}

// ---------- fused 128x128 LDS-tiled projection GEMM, both node types ----------
// K chunked by 16 (16.6 KB LDS) for 4 blocks/CU residency.
__global__ __launch_bounds__(256, 4)
void gemm_tile2(const float* __restrict__ xa, const float* __restrict__ xb,
                const float* __restrict__ WcA, const float* __restrict__ WcB,
                const float* __restrict__ bcA, const float* __restrict__ bcB,
                float* __restrict__ qbuf, float* __restrict__ ktv,
                int Na, int Nb, int nba, int nbb) {
  __shared__ float xs[16][132];
  __shared__ float ws[16][128];
  int bid = blockIdx.x;
  bool typeA = bid < nba*5;
  const float *x, *Wc, *bc;
  int nrows, r0, ct, OUT;
  if (typeA) { ct = bid / nba; int rb = bid % nba; x = xa; Wc = WcA; bc = bcA; nrows = Na; r0 = rb*128; OUT = 640; }
  else { int idx = bid - nba*5; ct = idx / nbb; int rb = idx % nbb; x = xb; Wc = WcB; bc = bcB; nrows = Nb; r0 = rb*128; OUT = 384; }
  int tid = threadIdx.x;
  int ty = tid >> 4, tx = tid & 15;
  float acc[8][8] = {};
  for (int kc = 0; kc < 128; kc += 16) {
    __syncthreads();
#pragma unroll
    for (int it = 0; it < 2; it++) {          // stage x chunk, transposed (512 float4)
      int idx = it*256 + tid;
      int r = idx >> 2;
      int k4 = (idx & 3) << 2;
      int row = r0 + r;
      float4 v = (row < nrows) ? *(const float4*)(x + (size_t)row*128 + kc + k4)
                               : make_float4(0.f, 0.f, 0.f, 0.f);
      xs[k4+0][r] = v.x; xs[k4+1][r] = v.y; xs[k4+2][r] = v.z; xs[k4+3][r] = v.w;
    }
#pragma unroll
    for (int it = 0; it < 2; it++) {          // stage W chunk (512 float4)
      int idx = it*256 + tid;
      int k = idx >> 5;
      int c4 = (idx & 31) << 2;
      *(float4*)&ws[k][c4] = *(const float4*)(Wc + (size_t)(kc + k)*OUT + ct*128 + c4);
    }
    __syncthreads();
#pragma unroll
    for (int k = 0; k < 16; k++) {
      float4 a0 = *(const float4*)&xs[k][ty*4];
      float4 a1 = *(const float4*)&xs[k][64 + ty*4];
      float4 b0 = *(const float4*)&ws[k][tx*4];
      float4 b1 = *(const float4*)&ws[k][64 + tx*4];
      float av[8] = {a0.x,a0.y,a0.z,a0.w,a1.x,a1.y,a1.z,a1.w};
      float bv[8] = {b0.x,b0.y,b0.z,b0.w,b1.x,b1.y,b1.z,b1.w};
#pragma unroll
      for (int i = 0; i < 8; i++)
#pragma unroll
        for (int j = 0; j < 8; j++)
          acc[i][j] += av[i]*bv[j];
    }
  }
  bool isq = (ct == 0);
  int qoff = typeA ? 0 : Na;
  int sbase = 0, cofs = 0;
  if (!isq) {
    if (typeA) { if (ct <= 2) { sbase = 0;  cofs = (ct-1)*128; } else { sbase = Na; cofs = (ct-3)*128; } }
    else       { sbase = 2*Na; cofs = (ct-1)*128; }
  }
#pragma unroll
  for (int i = 0; i < 8; i++) {
    int r = (i < 4) ? (ty*4 + i) : (64 + ty*4 + i - 4);
    int row = r0 + r;
    if (row >= nrows) continue;
#pragma unroll
    for (int half = 0; half < 2; half++) {
      int c0 = half*64 + tx*4;
      float4 v;
      v.x = acc[i][half*4+0] + bc[ct*128 + c0 + 0];
      v.y = acc[i][half*4+1] + bc[ct*128 + c0 + 1];
      v.z = acc[i][half*4+2] + bc[ct*128 + c0 + 2];
      v.w = acc[i][half*4+3] + bc[ct*128 + c0 + 3];
      if (isq) *(float4*)(qbuf + (size_t)(qoff + row)*128 + c0) = v;
      else     *(float4*)(ktv + (size_t)(sbase + row)*256 + cofs + c0) = v;
    }
  }
}

// ---------- tiled finish: gelu(agg)@Wout + gated skip, fused LN (L0) / x1 (L2) ----------
// mode: 0 = LN then gelu (layer 0); 1 = gelu; 2 = gelu + write x1 = dot(h, Wgat)
__global__ __launch_bounds__(256, 4)
void finish_tile(const float* __restrict__ agg,
                 const float* __restrict__ xa, const float* __restrict__ xb,
                 float* __restrict__ ha, float* __restrict__ hb,
                 const float* __restrict__ WoL, const float* __restrict__ boL,
                 const float* __restrict__ skipL,
                 const float* __restrict__ lng, const float* __restrict__ lnb,
                 const float* __restrict__ Wg, float* __restrict__ x1,
                 int mode, int Na, int Nb) {
  __shared__ float xs[16][132];
  __shared__ float ws[16][128];
  int nba = (Na + 127) >> 7;
  const float *xsrc, *Wo, *bo; float* h; float sgraw; int nrows, r0, aggoff, po;
  if ((int)blockIdx.x < nba) {
    xsrc = xa; h = ha; Wo = WoL; bo = boL; sgraw = skipL[0];
    nrows = Na; r0 = blockIdx.x*128; aggoff = 0; po = 0;
  } else {
    xsrc = xb; h = hb; Wo = WoL + 16384; bo = boL + 128; sgraw = skipL[1];
    nrows = Nb; r0 = ((int)blockIdx.x - nba)*128; aggoff = Na; po = 128;
  }
  int tid = threadIdx.x;
  int ty = tid >> 4, tx = tid & 15;
  float acc[8][8] = {};
  for (int kc = 0; kc < 128; kc += 16) {
    __syncthreads();
#pragma unroll
    for (int it = 0; it < 2; it++) {
      int idx = it*256 + tid;
      int r = idx >> 2;
      int k4 = (idx & 3) << 2;
      int row = r0 + r;
      float4 v = (row < nrows)
        ? *(const float4*)(agg + (size_t)(aggoff + row)*128 + kc + k4)
        : make_float4(0.f, 0.f, 0.f, 0.f);
      xs[k4+0][r] = gelu_f(v.x); xs[k4+1][r] = gelu_f(v.y);
      xs[k4+2][r] = gelu_f(v.z); xs[k4+3][r] = gelu_f(v.w);
    }
#pragma unroll
    for (int it = 0; it < 2; it++) {
      int idx = it*256 + tid;
      int k = idx >> 5;
      int c4 = (idx & 31) << 2;
      *(float4*)&ws[k][c4] = *(const float4*)(Wo + (size_t)(kc + k)*128 + c4);
    }
    __syncthreads();
#pragma unroll
    for (int k = 0; k < 16; k++) {
      float4 a0 = *(const float4*)&xs[k][ty*4];
      float4 a1 = *(const float4*)&xs[k][64 + ty*4];
      float4 b0 = *(const float4*)&ws[k][tx*4];
      float4 b1 = *(const float4*)&ws[k][64 + tx*4];
      float av[8] = {a0.x,a0.y,a0.z,a0.w,a1.x,a1.y,a1.z,a1.w};
      float bv[8] = {b0.x,b0.y,b0.z,b0.w,b1.x,b1.y,b1.z,b1.w};
#pragma unroll
      for (int i = 0; i < 8; i++)
#pragma unroll
        for (int j = 0; j < 8; j++)
          acc[i][j] += av[i]*bv[j];
    }
  }
  float sg = 1.f/(1.f + expf(-sgraw));
#pragma unroll
  for (int i = 0; i < 8; i++) {
    int r = (i < 4) ? (ty*4 + i) : (64 + ty*4 + i - 4);
    int row = r0 + r;
    if (row >= nrows) continue;
    int c0 = tx*4, c1 = 64 + tx*4;
    float4 xv0 = *(const float4*)(xsrc + (size_t)row*128 + c0);
    float4 xv1 = *(const float4*)(xsrc + (size_t)row*128 + c1);
    float v[8];
    v[0] = sg*(acc[i][0] + bo[c0+0]) + (1.f-sg)*xv0.x;
    v[1] = sg*(acc[i][1] + bo[c0+1]) + (1.f-sg)*xv0.y;
    v[2] = sg*(acc[i][2] + bo[c0+2]) + (1.f-sg)*xv0.z;
    v[3] = sg*(acc[i][3] + bo[c0+3]) + (1.f-sg)*xv0.w;
    v[4] = sg*(acc[i][4] + bo[c1+0]) + (1.f-sg)*xv1.x;
    v[5] = sg*(acc[i][5] + bo[c1+1]) + (1.f-sg)*xv1.y;
    v[6] = sg*(acc[i][6] + bo[c1+2]) + (1.f-sg)*xv1.z;
    v[7] = sg*(acc[i][7] + bo[c1+3]) + (1.f-sg)*xv1.w;
    if (mode == 0) {
      float sum = v[0]+v[1]+v[2]+v[3]+v[4]+v[5]+v[6]+v[7];
      sum += __shfl_xor(sum, 1, 64); sum += __shfl_xor(sum, 2, 64);
      sum += __shfl_xor(sum, 4, 64); sum += __shfl_xor(sum, 8, 64);
      float mu = sum * (1.f/128.f);
      float var = 0.f;
#pragma unroll
      for (int j = 0; j < 8; j++) { float d = v[j]-mu; var += d*d; }
      var += __shfl_xor(var, 1, 64); var += __shfl_xor(var, 2, 64);
      var += __shfl_xor(var, 4, 64); var += __shfl_xor(var, 8, 64);
      float inv = 1.f / sqrtf(var*(1.f/128.f) + 1e-5f);
#pragma unroll
      for (int j = 0; j < 8; j++) {
        int c = (j < 4) ? (c0 + j) : (c1 + j - 4);
        v[j] = gelu_f((v[j]-mu)*inv*lng[po + c] + lnb[po + c]);
      }
    } else {
#pragma unroll
      for (int j = 0; j < 8; j++) v[j] = gelu_f(v[j]);
    }
    float4 o0; o0.x=v[0]; o0.y=v[1]; o0.z=v[2]; o0.w=v[3];
    float4 o1; o1.x=v[4]; o1.y=v[5]; o1.z=v[6]; o1.w=v[7];
    *(float4*)(h + (size_t)row*128 + c0) = o0;
    *(float4*)(h + (size_t)row*128 + c1) = o1;
    if (mode == 2) {
      float s1 = v[0]*Wg[c0+0] + v[1]*Wg[c0+1] + v[2]*Wg[c0+2] + v[3]*Wg[c0+3]
               + v[4]*Wg[c1+0] + v[5]*Wg[c1+1] + v[6]*Wg[c1+2] + v[7]*Wg[c1+3];
      s1 += __shfl_xor(s1, 1, 64); s1 += __shfl_xor(s1, 2, 64);
      s1 += __shfl_xor(s1, 4, 64); s1 += __shfl_xor(s1, 8, 64);
      if (tx == 0) x1[(size_t)aggoff ? (size_t)row + Na : (size_t)row] = s1;
    }
  }
}

// ---------- CSR build (dst-sorted; pure edges, no self loops) ----------
__global__ void hist_init(int* __restrict__ hist, int N) {
  int i = blockIdx.x*blockDim.x + threadIdx.x;
  if (i < N) hist[i] = 0;
}
__global__ void hist_count_all(const int* __restrict__ aa, const int* __restrict__ ab,
                               const int* __restrict__ ba,
                               int Eaa, int Eab, int Eba, int Na, int* __restrict__ hist) {
  int i = blockIdx.x*blockDim.x + threadIdx.x;
  int tot = Eaa + Eab + Eba;
  if (i >= tot) return;
  int dst;
  if (i < Eaa)            dst = aa[Eaa + i];
  else if (i < Eaa + Eab) dst = ab[Eab + (i - Eaa)] + Na;
  else                    dst = ba[Eba + (i - Eaa - Eab)];
  atomicAdd(hist + dst, 1);
}
__global__ void scan_part(const int* __restrict__ hist, int* __restrict__ bsum, int N) {
  __shared__ int sd[256];
  int t = threadIdx.x;
  int i = blockIdx.x*256 + t;
  sd[t] = (i < N) ? hist[i] : 0;
  __syncthreads();
  for (int o = 128; o; o >>= 1) { if (t < o) sd[t] += sd[t+o]; __syncthreads(); }
  if (t == 0) bsum[blockIdx.x] = sd[0];
}
__global__ void scan_bsum(int* __restrict__ bsum, int nb) {
  __shared__ int sd[1024];
  int t = threadIdx.x;
  sd[t] = (t < nb) ? bsum[t] : 0;
  __syncthreads();
  for (int o = 1; o < 1024; o <<= 1) {
    int v = (t >= o) ? sd[t-o] : 0;
    __syncthreads();
    sd[t] += v;
    __syncthreads();
  }
  if (t < nb) bsum[t] = sd[t];
}
__global__ void scan_fill(const int* __restrict__ hist, const int* __restrict__ bsum,
                          int* __restrict__ roff, int* __restrict__ cursor, int N) {
  __shared__ int sd[256];
  int t = threadIdx.x;
  int i = blockIdx.x*256 + t;
  int v = (i < N) ? hist[i] : 0;
  sd[t] = v;
  __syncthreads();
  for (int o = 1; o < 256; o <<= 1) {
    int u = (t >= o) ? sd[t-o] : 0;
    __syncthreads();
    sd[t] += u;
    __syncthreads();
  }
  int boff = (blockIdx.x == 0) ? 0 : bsum[blockIdx.x - 1];
  if (i < N) {
    int excl = boff + sd[t] - v;
    roff[i] = excl;
    cursor[i] = excl;
    if (i == N - 1) roff[N] = boff + sd[t];
  }
}
__global__ void fill_all(const int* __restrict__ aa, const int* __restrict__ ab,
                         const int* __restrict__ ba,
                         int Eaa, int Eab, int Eba, int Na,
                         int* __restrict__ cursor, int* __restrict__ epack) {
  int i = blockIdx.x*blockDim.x + threadIdx.x;
  int tot = Eaa + Eab + Eba;
  if (i >= tot) return;
  int dst, slot;
  if (i < Eaa)            { dst = aa[Eaa + i];                slot = aa[i]; }
  else if (i < Eaa + Eab) { int j = i - Eaa;       dst = ab[Eab + j] + Na; slot = ab[j] + Na; }
  else                    { int j = i - Eaa - Eab; dst = ba[Eba + j];      slot = ba[j] + 2*Na; }
  int pos = atomicAdd(cursor + dst, 1);
  epack[pos] = slot;
}

// ---------- fused HGT attention, 4-way edge-parallel, depth-2 prefetch ----------
__global__ void seg_attn(const float* __restrict__ qbuf,
                         const float* __restrict__ ktv,
                         const int* __restrict__ roff, const int* __restrict__ epack,
                         float* __restrict__ agg, int Na, int N) {
  int wid = (blockIdx.x*blockDim.x + threadIdx.x) >> 6;
  int lane = threadIdx.x & 63;
  if (wid >= N) return;
  int quarter = lane >> 4;
  int u = lane & 15;
  int h = u >> 2;
  int d0 = (u & 3) * 8;
  const float* qp = qbuf + (size_t)wid*128 + h*32 + d0;
  float4 qa = *(const float4*)qp;
  float4 qb = *(const float4*)(qp + 4);
  int beg = roff[wid], end = roff[wid + 1];
  float m = -1e30f, s = 0.f;
  float4 aA = make_float4(0.f,0.f,0.f,0.f), aB = make_float4(0.f,0.f,0.f,0.f);
  int i = beg + quarter;
  float4 ka0, kb0, va0, vb0, ka1, kb1, va1, vb1;
  if (i < end) {
    const float* kp = ktv + (size_t)epack[i]*256 + h*64 + d0;
    ka0 = *(const float4*)kp;      kb0 = *(const float4*)(kp + 4);
    va0 = *(const float4*)(kp+32); vb0 = *(const float4*)(kp + 36);
  }
  if (i + 4 < end) {
    const float* kp = ktv + (size_t)epack[i+4]*256 + h*64 + d0;
    ka1 = *(const float4*)kp;      kb1 = *(const float4*)(kp + 4);
    va1 = *(const float4*)(kp+32); vb1 = *(const float4*)(kp + 36);
  }
  for (; i < end; i += 4) {
    float4 cka = ka0, ckb = kb0, cva = va0, cvb = vb0;
    ka0 = ka1; kb0 = kb1; va0 = va1; vb0 = vb1;
    int nx = i + 8;
    if (nx < end) {
      const float* kp = ktv + (size_t)epack[nx]*256 + h*64 + d0;
      ka1 = *(const float4*)kp;      kb1 = *(const float4*)(kp + 4);
      va1 = *(const float4*)(kp+32); vb1 = *(const float4*)(kp + 36);
    }
    float sc = qa.x*cka.x + qa.y*cka.y + qa.z*cka.z + qa.w*cka.w
             + qb.x*ckb.x + qb.y*ckb.y + qb.z*ckb.z + qb.w*ckb.w;
    sc += __shfl_xor(sc, 1, 64);
    sc += __shfl_xor(sc, 2, 64);
    float nm = fmaxf(m, sc);
    float scale = exp2f(m - nm);
    float e = exp2f(sc - nm);
    s = s*scale + e;
    aA.x = aA.x*scale + e*cva.x; aA.y = aA.y*scale + e*cva.y;
    aA.z = aA.z*scale + e*cva.z; aA.w = aA.w*scale + e*cva.w;
    aB.x = aB.x*scale + e*cvb.x; aB.y = aB.y*scale + e*cvb.y;
    aB.z = aB.z*scale + e*cvb.z; aB.w = aB.w*scale + e*cvb.w;
    m = nm;
  }
#pragma unroll
  for (int off = 16; off <= 32; off <<= 1) {
    float mo = __shfl_xor(m, off, 64);
    float so = __shfl_xor(s, off, 64);
    float A0 = __shfl_xor(aA.x, off, 64), A1 = __shfl_xor(aA.y, off, 64);
    float A2 = __shfl_xor(aA.z, off, 64), A3 = __shfl_xor(aA.w, off, 64);
    float B0 = __shfl_xor(aB.x, off, 64), B1 = __shfl_xor(aB.y, off, 64);
    float B2 = __shfl_xor(aB.z, off, 64), B3 = __shfl_xor(aB.w, off, 64);
    float nm = fmaxf(m, mo);
    float c1 = exp2f(m - nm), c2 = exp2f(mo - nm);
    s = s*c1 + so*c2;
    aA.x = aA.x*c1 + A0*c2; aA.y = aA.y*c1 + A1*c2;
    aA.z = aA.z*c1 + A2*c2; aA.w = aA.w*c1 + A3*c2;
    aB.x = aB.x*c1 + B0*c2; aB.y = aB.y*c1 + B1*c2;
    aB.z = aB.z*c1 + B2*c2; aB.w = aB.w*c1 + B3*c2;
    m = nm;
  }
  if (quarter == 0) {
    float inv = 1.f / (s + 1e-16f);
    float4 o1, o2;
    o1.x = aA.x*inv; o1.y = aA.y*inv; o1.z = aA.z*inv; o1.w = aA.w*inv;
    o2.x = aB.x*inv; o2.y = aB.y*inv; o2.z = aB.z*inv; o2.w = aB.w*inv;
    float* op = agg + (size_t)wid*128 + h*32 + d0;
    *(float4*)op = o1;
    *(float4*)(op + 4) = o2;
  }
}

// fused GAT scorer via CSR
__global__ void gat_all(const float* __restrict__ x1, const int* __restrict__ roff,
                        const int* __restrict__ epack,
                        const float* __restrict__ asrc, const float* __restrict__ adst,
                        int Na, int N, float* __restrict__ score) {
  int n = blockIdx.x*blockDim.x + threadIdx.x;
  if (n >= N) return;
  float xd = x1[n];
  float as_ = asrc[0], ad = adst[0];
  float e0 = xd*as_ + xd*ad;
  e0 = (e0 > 0.f) ? e0 : 0.2f*e0;
  float m = e0, s = 1.f, acc = xd;
  int beg = roff[n], end = roff[n + 1];
  for (int i = beg; i < end; i++) {
    int slot = epack[i];
    int sg = (slot < Na) ? slot : slot - Na;
    float xs = x1[sg];
    float e = xs*as_ + xd*ad;
    e = (e > 0.f) ? e : 0.2f*e;
    float nm = fmaxf(m, e);
    float sc = __expf(m - nm), ee = __expf(e - nm);
    s = s*sc + ee;  acc = acc*sc + ee*xs;  m = nm;
  }
  score[n] = acc / (s + 1e-16f);
}

// ---- parallel top-8 ----
__global__ void topk_stage1(const float* __restrict__ score, const float* __restrict__ bgat,
                            int N, float* __restrict__ cvals, int* __restrict__ cidx) {
  __shared__ float bv[256];
  __shared__ int   bi[256];
  int t = threadIdx.x;
  int chunk = (N + gridDim.x - 1) / gridDim.x;
  int i = blockIdx.x * chunk + t;
  float bg = bgat[0];
  bool valid = (t < chunk && i < N);
  float myv = valid ? score[i] + bg : -INFINITY;
  int   myi = valid ? i : 0x7FFFFFFF;
  for (int k = 0; k < 8; k++) {
    bv[t] = myv; bi[t] = myi;
    __syncthreads();
    for (int o = 128; o; o >>= 1) {
      if (t < o) {
        if (bv[t+o] > bv[t] || (bv[t+o] == bv[t] && bi[t+o] < bi[t])) { bv[t]=bv[t+o]; bi[t]=bi[t+o]; }
      }
      __syncthreads();
    }
    if (t == 0) { cvals[blockIdx.x*8 + k] = bv[0]; cidx[blockIdx.x*8 + k] = bi[0]; }
    if (myi == bi[0]) myv = -INFINITY;
    __syncthreads();
  }
}

// merged: top-8 merge + scorer-gated MLP head (single block)
__global__ void topk_mlp(const float* __restrict__ cvals, const int* __restrict__ cidx, int C,
                         const float* __restrict__ h,
                         const float* __restrict__ W1, const float* __restrict__ b1,
                         const float* __restrict__ W2, const float* __restrict__ b2,
                         const float* __restrict__ W3, const float* __restrict__ b3,
                         float* __restrict__ out) {
  __shared__ float bv[256];
  __shared__ int   bi[256];
  __shared__ int   seli[8];
  __shared__ float sval[8];
  __shared__ float hp[1024], v1[128], v2[64];
  int t = threadIdx.x;
  for (int k = 0; k < 8; k++) {
    float best = -INFINITY; int besti = 0x7FFFFFFF;
    for (int i = t; i < C; i += 256) {
      int id = cidx[i];
      bool taken = false;
      for (int j = 0; j < k; j++) if (seli[j] == id) taken = true;
      if (taken) continue;
      float v = cvals[i];
      if (v > best || (v == best && id < besti)) { best = v; besti = id; }
    }
    bv[t] = best; bi[t] = besti;
    __syncthreads();
    for (int o = 128; o; o >>= 1) {
      if (t < o) {
        if (bv[t+o] > bv[t] || (bv[t+o] == bv[t] && bi[t+o] < bi[t])) { bv[t]=bv[t+o]; bi[t]=bi[t+o]; }
      }
      __syncthreads();
    }
    if (t == 0) { seli[k] = bi[0]; sval[k] = bv[0]; }
    __syncthreads();
  }
  for (int i = t; i < 1024; i += 256) {
    int r = i >> 7, d = i & 127;
    hp[i] = h[(size_t)seli[r]*128 + d] * tanhf(sval[r]);
  }
  __syncthreads();
  if (t < 128) {
    float a = 0.f;
    for (int k = 0; k < 1024; k++) a += hp[k]*W1[(size_t)k*128 + t];
    v1[t] = gelu_f(a + b1[t]);
  }
  __syncthreads();
  if (t < 64) {
    float a = 0.f;
    for (int k = 0; k < 128; k++) a += v1[k]*W2[(size_t)k*64 + t];
    v2[t] = gelu_f(a + b2[t]);
  }
  __syncthreads();
  if (t < 16) {
    float a = 0.f;
    for (int k = 0; k < 64; k++) a += v2[k]*W3[(size_t)k*16 + t];
    float r = gelu_f(a + b3[t]);
    if (isnan(r)) r = 0.f;
    else if (isinf(r)) r = (r > 0.f) ? 3.4028234663852886e38f : -3.4028234663852886e38f;
    out[t] = r;
  }
}

extern "C" void kernel_launch(void* const* d_in, const int* in_sizes, int n_in,
                              void* d_out, int out_size, void* d_ws, size_t ws_size,
                              hipStream_t stream) {
  const float* x_a  = (const float*)d_in[0];
  const float* x_b  = (const float*)d_in[1];
  const int* ei_aa  = (const int*)d_in[2];
  const int* ei_ab  = (const int*)d_in[3];
  const int* ei_ba  = (const int*)d_in[4];
  const float* Wkqv = (const float*)d_in[5];
  const float* bkqv = (const float*)d_in[6];
  const float* Wout = (const float*)d_in[7];
  const float* bout = (const float*)d_in[8];
  const float* skip = (const float*)d_in[9];
  const float* arel = (const float*)d_in[10];
  const float* mrel = (const float*)d_in[11];
  const float* prel = (const float*)d_in[12];
  const float* ln_g = (const float*)d_in[13];
  const float* ln_b = (const float*)d_in[14];
  const float* Wgat = (const float*)d_in[15];
  const float* att_src = (const float*)d_in[16];
  const float* att_dst = (const float*)d_in[17];
  const float* bgat = (const float*)d_in[18];
  const float* W1 = (const float*)d_in[19];
  const float* b1 = (const float*)d_in[20];
  const float* W2 = (const float*)d_in[21];
  const float* b2 = (const float*)d_in[22];
  const float* W3 = (const float*)d_in[23];
  const float* b3 = (const float*)d_in[24];

  int Na = in_sizes[0]/128, Nb = in_sizes[1]/128, N = Na + Nb;
  int Eaa = in_sizes[2]/2, Eab = in_sizes[3]/2, Eba = in_sizes[4]/2;
  int Etot = Eaa + Eab + Eba;

  float* w = (float*)d_ws;
  size_t off = 0;
  auto alloc = [&](size_t n) { float* p = w + off; off += n; return p; };
  float* hbuf  = alloc((size_t)N*128);
  float* qbuf  = alloc((size_t)N*128);
  float* ktvA  = alloc((size_t)(2*Na + Nb)*256);
  float* agg   = alloc((size_t)N*128);
  float* Wc    = alloc((size_t)3*1024*128);
  float* bc    = alloc((size_t)3*1024);
  float* x1buf = alloc((size_t)N);
  float* score = alloc((size_t)N);
  float* cvals = alloc(2048);
  int*   cidx  = (int*)alloc(2048);
  int*   hist  = (int*)alloc((size_t)N);
  int*   roff  = (int*)alloc((size_t)N + 1);
  int*   cursor= (int*)alloc((size_t)N);
  int*   bsum  = (int*)alloc(1024);
  int*   epack = (int*)alloc((size_t)Etot);

  float* h_a = hbuf;
  float* h_b = hbuf + (size_t)Na*128;

  mkw<<<dim3(3*1024),dim3(128),0,stream>>>(Wkqv, bkqv, arel, mrel, prel, Wc, bc);

  int nsb = (N + 255)/256;
  hist_init<<<dim3(nsb),dim3(256),0,stream>>>(hist, N);
  hist_count_all<<<dim3((Etot+255)/256),dim3(256),0,stream>>>(ei_aa, ei_ab, ei_ba, Eaa, Eab, Eba, Na, hist);
  scan_part<<<dim3(nsb),dim3(256),0,stream>>>(hist, bsum, N);
  scan_bsum<<<dim3(1),dim3(1024),0,stream>>>(bsum, nsb);
  scan_fill<<<dim3(nsb),dim3(256),0,stream>>>(hist, bsum, roff, cursor, N);
  fill_all<<<dim3((Etot+255)/256),dim3(256),0,stream>>>(ei_aa, ei_ab, ei_ba, Eaa, Eab, Eba, Na, cursor, epack);

  int nba = (Na + 127)/128, nbb = (Nb + 127)/128;

  for (int L = 0; L < 3; L++) {
    const float* xa_in = (L == 0) ? x_a : h_a;
    const float* xb_in = (L == 0) ? x_b : h_b;
    const float* WcA = Wc + (size_t)L*1024*128;
    const float* WcB = WcA + (size_t)640*128;
    const float* bcA = bc + (size_t)L*1024;
    const float* bcB = bcA + 640;
    gemm_tile2<<<dim3(nba*5 + nbb*3),dim3(256),0,stream>>>(xa_in, xb_in, WcA, WcB, bcA, bcB,
                                                           qbuf, ktvA, Na, Nb, nba, nbb);
    seg_attn<<<dim3((N+3)/4),dim3(256),0,stream>>>(qbuf, ktvA, roff, epack, agg, Na, N);
    int mode = (L == 0) ? 0 : (L == 2 ? 2 : 1);
    finish_tile<<<dim3(nba + nbb),dim3(256),0,stream>>>(agg, xa_in, xb_in, h_a, h_b,
                                                        Wout + (size_t)L*2*16384,
                                                        bout + (size_t)L*2*128,
                                                        skip + L*2, ln_g, ln_b,
                                                        Wgat, x1buf, mode, Na, Nb);
  }

  gat_all<<<dim3((N+255)/256),dim3(256),0,stream>>>(x1buf, roff, epack, att_src, att_dst, Na, N, score);
  int tk_blocks = (N + 255)/256;
  topk_stage1<<<dim3(tk_blocks),dim3(256),0,stream>>>(score, bgat, N, cvals, cidx);
  topk_mlp<<<dim3(1),dim3(256),0,stream>>>(cvals, cidx, tk_blocks*8, hbuf,
                                           W1, b1, W2, b2, W3, b3, (float*)d_out);
}

// Round 14
// 752.043 us; speedup vs baseline: 1.1146x; 1.1146x over previous
//
#include <hip/hip_runtime.h>
#include <math.h>

#define HID 128

__device__ __forceinline__ float gelu_f(float x){
  return 0.5f*x*(1.0f+erff(x*0.70710678118654752440f));
}

// ---------- combined-weight precompute ----------
__global__ void mkw(const float* __restrict__ Wkqv, const float* __restrict__ bkqv,
                    const float* __restrict__ arel, const float* __restrict__ mrel,
                    const float* __restrict__ prel,
                    float* __restrict__ Wc, float* __restrict__ bc) {
  int L = blockIdx.x >> 10;
  int j = blockIdx.x & 1023;
  int t = threadIdx.x;
  int type = (j < 640) ? 0 : 1;
  int jj = (j < 640) ? j : j - 640;
  const float* W    = Wkqv + ((size_t)L*2 + type)*49152;
  const float* bsrc = bkqv + ((size_t)L*2 + type)*384;
  int stride = type ? 384 : 640;
  float* Wdst = Wc + (size_t)L*(640+384)*128 + (type ? (size_t)640*128 : 0);
  float* bdst = bc + (size_t)L*1024 + (type ? 640 : 0);
  float val, bval;
  if (jj < 128) {
    val  = W[(size_t)t*384 + 128 + jj];
    bval = bsrc[128 + jj];
  } else {
    int u = jj - 128;
    int et = type ? 2 : (u >> 8);
    int r = u & 255;
    int h = r >> 6, wofs = r & 63;
    const float* rel; int coloff; float scl;
    if (wofs < 32) {
      rel = arel + ((size_t)L*3 + et)*4096 + (size_t)h*32*32 + wofs;
      coloff = h*32;
      scl = prel[((size_t)L*3 + et)*4 + h] * 0.17677669529663688f * 1.4426950408889634f;
    } else {
      rel = mrel + ((size_t)L*3 + et)*4096 + (size_t)h*32*32 + (wofs - 32);
      coloff = 256 + h*32;
      scl = 1.0f;
    }
    float a = 0.f, bb = 0.f;
    for (int d = 0; d < 32; d++) {
      float rv = rel[(size_t)d*32];
      a  += W[(size_t)t*384 + coloff + d] * rv;
      bb += bsrc[coloff + d] * rv;
    }
    val = a * scl; bval = bb * scl;
  }
  Wdst[(size_t)t*stride + jj] = val;
  if (t == 0) bdst[jj] = bval;
}

// ---------- fused 128x128 LDS-tiled projection GEMM, both node types ----------
// K chunked by 16 (16.6 KB LDS); grid 1256 blocks -> ~5/CU.
__global__ __launch_bounds__(256, 4)
void gemm_tile2(const float* __restrict__ xa, const float* __restrict__ xb,
                const float* __restrict__ WcA, const float* __restrict__ WcB,
                const float* __restrict__ bcA, const float* __restrict__ bcB,
                float* __restrict__ qbuf, float* __restrict__ ktv,
                int Na, int Nb, int nba, int nbb) {
  __shared__ float xs[16][132];
  __shared__ float ws[16][128];
  int bid = blockIdx.x;
  bool typeA = bid < nba*5;
  const float *x, *Wc, *bc;
  int nrows, r0, ct, OUT;
  if (typeA) { ct = bid / nba; int rb = bid % nba; x = xa; Wc = WcA; bc = bcA; nrows = Na; r0 = rb*128; OUT = 640; }
  else { int idx = bid - nba*5; ct = idx / nbb; int rb = idx % nbb; x = xb; Wc = WcB; bc = bcB; nrows = Nb; r0 = rb*128; OUT = 384; }
  int tid = threadIdx.x;
  int ty = tid >> 4, tx = tid & 15;
  float acc[8][8] = {};
  for (int kc = 0; kc < 128; kc += 16) {
    __syncthreads();
#pragma unroll
    for (int it = 0; it < 2; it++) {
      int idx = it*256 + tid;
      int r = idx >> 2;
      int k4 = (idx & 3) << 2;
      int row = r0 + r;
      float4 v = (row < nrows) ? *(const float4*)(x + (size_t)row*128 + kc + k4)
                               : make_float4(0.f, 0.f, 0.f, 0.f);
      xs[k4+0][r] = v.x; xs[k4+1][r] = v.y; xs[k4+2][r] = v.z; xs[k4+3][r] = v.w;
    }
#pragma unroll
    for (int it = 0; it < 2; it++) {
      int idx = it*256 + tid;
      int k = idx >> 5;
      int c4 = (idx & 31) << 2;
      *(float4*)&ws[k][c4] = *(const float4*)(Wc + (size_t)(kc + k)*OUT + ct*128 + c4);
    }
    __syncthreads();
#pragma unroll
    for (int k = 0; k < 16; k++) {
      float4 a0 = *(const float4*)&xs[k][ty*4];
      float4 a1 = *(const float4*)&xs[k][64 + ty*4];
      float4 b0 = *(const float4*)&ws[k][tx*4];
      float4 b1 = *(const float4*)&ws[k][64 + tx*4];
      float av[8] = {a0.x,a0.y,a0.z,a0.w,a1.x,a1.y,a1.z,a1.w};
      float bv[8] = {b0.x,b0.y,b0.z,b0.w,b1.x,b1.y,b1.z,b1.w};
#pragma unroll
      for (int i = 0; i < 8; i++)
#pragma unroll
        for (int j = 0; j < 8; j++)
          acc[i][j] += av[i]*bv[j];
    }
  }
  bool isq = (ct == 0);
  int qoff = typeA ? 0 : Na;
  int sbase = 0, cofs = 0;
  if (!isq) {
    if (typeA) { if (ct <= 2) { sbase = 0;  cofs = (ct-1)*128; } else { sbase = Na; cofs = (ct-3)*128; } }
    else       { sbase = 2*Na; cofs = (ct-1)*128; }
  }
#pragma unroll
  for (int i = 0; i < 8; i++) {
    int r = (i < 4) ? (ty*4 + i) : (64 + ty*4 + i - 4);
    int row = r0 + r;
    if (row >= nrows) continue;
#pragma unroll
    for (int half = 0; half < 2; half++) {
      int c0 = half*64 + tx*4;
      float4 v;
      v.x = acc[i][half*4+0] + bc[ct*128 + c0 + 0];
      v.y = acc[i][half*4+1] + bc[ct*128 + c0 + 1];
      v.z = acc[i][half*4+2] + bc[ct*128 + c0 + 2];
      v.w = acc[i][half*4+3] + bc[ct*128 + c0 + 3];
      if (isq) *(float4*)(qbuf + (size_t)(qoff + row)*128 + c0) = v;
      else     *(float4*)(ktv + (size_t)(sbase + row)*256 + cofs + c0) = v;
    }
  }
}

// ---------- tiled finish: 64-row tiles (628 blocks), K=32 chunks ----------
// mode: 0 = LN then gelu (layer 0); 1 = gelu; 2 = gelu + write x1 = dot(h, Wgat)
__global__ __launch_bounds__(256, 3)
void finish_tile(const float* __restrict__ agg,
                 const float* __restrict__ xa, const float* __restrict__ xb,
                 float* __restrict__ ha, float* __restrict__ hb,
                 const float* __restrict__ WoL, const float* __restrict__ boL,
                 const float* __restrict__ skipL,
                 const float* __restrict__ lng, const float* __restrict__ lnb,
                 const float* __restrict__ Wg, float* __restrict__ x1,
                 int mode, int Na, int Nb) {
  __shared__ float xs[32][68];    // [k][row], 64 rows + pad
  __shared__ float ws[32][128];   // [k][col]
  int nba = (Na + 63) >> 6;
  const float *xsrc, *Wo, *bo; float* h; float sgraw; int nrows, r0, aggoff, po;
  if ((int)blockIdx.x < nba) {
    xsrc = xa; h = ha; Wo = WoL; bo = boL; sgraw = skipL[0];
    nrows = Na; r0 = blockIdx.x*64; aggoff = 0; po = 0;
  } else {
    xsrc = xb; h = hb; Wo = WoL + 16384; bo = boL + 128; sgraw = skipL[1];
    nrows = Nb; r0 = ((int)blockIdx.x - nba)*64; aggoff = Na; po = 128;
  }
  int tid = threadIdx.x;
  int ty = tid >> 4, tx = tid & 15;
  float acc[4][8] = {};
  for (int kc = 0; kc < 128; kc += 32) {
    __syncthreads();
#pragma unroll
    for (int it = 0; it < 2; it++) {          // stage gelu(agg): 64 rows x 32 k = 512 float4
      int idx = it*256 + tid;
      int r = idx >> 3;
      int k4 = (idx & 7) << 2;
      int row = r0 + r;
      float4 v = (row < nrows)
        ? *(const float4*)(agg + (size_t)(aggoff + row)*128 + kc + k4)
        : make_float4(0.f, 0.f, 0.f, 0.f);
      xs[k4+0][r] = gelu_f(v.x); xs[k4+1][r] = gelu_f(v.y);
      xs[k4+2][r] = gelu_f(v.z); xs[k4+3][r] = gelu_f(v.w);
    }
#pragma unroll
    for (int it = 0; it < 4; it++) {          // stage Wout: 32 k x 128 c = 1024 float4
      int idx = it*256 + tid;
      int k = idx >> 5;
      int c4 = (idx & 31) << 2;
      *(float4*)&ws[k][c4] = *(const float4*)(Wo + (size_t)(kc + k)*128 + c4);
    }
    __syncthreads();
#pragma unroll
    for (int k = 0; k < 32; k++) {
      float4 a0 = *(const float4*)&xs[k][ty*4];
      float4 b0 = *(const float4*)&ws[k][tx*4];
      float4 b1 = *(const float4*)&ws[k][64 + tx*4];
      float av[4] = {a0.x,a0.y,a0.z,a0.w};
      float bv[8] = {b0.x,b0.y,b0.z,b0.w,b1.x,b1.y,b1.z,b1.w};
#pragma unroll
      for (int i = 0; i < 4; i++)
#pragma unroll
        for (int j = 0; j < 8; j++)
          acc[i][j] += av[i]*bv[j];
    }
  }
  float sg = 1.f/(1.f + expf(-sgraw));
#pragma unroll
  for (int i = 0; i < 4; i++) {
    int row = r0 + ty*4 + i;
    if (row >= nrows) continue;   // 16 lanes of a row-group skip together
    int c0 = tx*4, c1 = 64 + tx*4;
    float4 xv0 = *(const float4*)(xsrc + (size_t)row*128 + c0);
    float4 xv1 = *(const float4*)(xsrc + (size_t)row*128 + c1);
    float v[8];
    v[0] = sg*(acc[i][0] + bo[c0+0]) + (1.f-sg)*xv0.x;
    v[1] = sg*(acc[i][1] + bo[c0+1]) + (1.f-sg)*xv0.y;
    v[2] = sg*(acc[i][2] + bo[c0+2]) + (1.f-sg)*xv0.z;
    v[3] = sg*(acc[i][3] + bo[c0+3]) + (1.f-sg)*xv0.w;
    v[4] = sg*(acc[i][4] + bo[c1+0]) + (1.f-sg)*xv1.x;
    v[5] = sg*(acc[i][5] + bo[c1+1]) + (1.f-sg)*xv1.y;
    v[6] = sg*(acc[i][6] + bo[c1+2]) + (1.f-sg)*xv1.z;
    v[7] = sg*(acc[i][7] + bo[c1+3]) + (1.f-sg)*xv1.w;
    if (mode == 0) {
      float sum = v[0]+v[1]+v[2]+v[3]+v[4]+v[5]+v[6]+v[7];
      sum += __shfl_xor(sum, 1, 64); sum += __shfl_xor(sum, 2, 64);
      sum += __shfl_xor(sum, 4, 64); sum += __shfl_xor(sum, 8, 64);
      float mu = sum * (1.f/128.f);
      float var = 0.f;
#pragma unroll
      for (int j = 0; j < 8; j++) { float d = v[j]-mu; var += d*d; }
      var += __shfl_xor(var, 1, 64); var += __shfl_xor(var, 2, 64);
      var += __shfl_xor(var, 4, 64); var += __shfl_xor(var, 8, 64);
      float inv = 1.f / sqrtf(var*(1.f/128.f) + 1e-5f);
#pragma unroll
      for (int j = 0; j < 8; j++) {
        int c = (j < 4) ? (c0 + j) : (c1 + j - 4);
        v[j] = gelu_f((v[j]-mu)*inv*lng[po + c] + lnb[po + c]);
      }
    } else {
#pragma unroll
      for (int j = 0; j < 8; j++) v[j] = gelu_f(v[j]);
    }
    float4 o0; o0.x=v[0]; o0.y=v[1]; o0.z=v[2]; o0.w=v[3];
    float4 o1; o1.x=v[4]; o1.y=v[5]; o1.z=v[6]; o1.w=v[7];
    *(float4*)(h + (size_t)row*128 + c0) = o0;
    *(float4*)(h + (size_t)row*128 + c1) = o1;
    if (mode == 2) {
      float s1 = v[0]*Wg[c0+0] + v[1]*Wg[c0+1] + v[2]*Wg[c0+2] + v[3]*Wg[c0+3]
               + v[4]*Wg[c1+0] + v[5]*Wg[c1+1] + v[6]*Wg[c1+2] + v[7]*Wg[c1+3];
      s1 += __shfl_xor(s1, 1, 64); s1 += __shfl_xor(s1, 2, 64);
      s1 += __shfl_xor(s1, 4, 64); s1 += __shfl_xor(s1, 8, 64);
      if (tx == 0) x1[(size_t)(aggoff ? row + Na : row)] = s1;
    }
  }
}

// ---------- CSR build (dst-sorted; pure edges, no self loops) ----------
__global__ void hist_init(int* __restrict__ hist, int N) {
  int i = blockIdx.x*blockDim.x + threadIdx.x;
  if (i < N) hist[i] = 0;
}
__global__ void hist_count_all(const int* __restrict__ aa, const int* __restrict__ ab,
                               const int* __restrict__ ba,
                               int Eaa, int Eab, int Eba, int Na, int* __restrict__ hist) {
  int i = blockIdx.x*blockDim.x + threadIdx.x;
  int tot = Eaa + Eab + Eba;
  if (i >= tot) return;
  int dst;
  if (i < Eaa)            dst = aa[Eaa + i];
  else if (i < Eaa + Eab) dst = ab[Eab + (i - Eaa)] + Na;
  else                    dst = ba[Eba + (i - Eaa - Eab)];
  atomicAdd(hist + dst, 1);
}
__global__ void scan_part(const int* __restrict__ hist, int* __restrict__ bsum, int N) {
  __shared__ int sd[256];
  int t = threadIdx.x;
  int i = blockIdx.x*256 + t;
  sd[t] = (i < N) ? hist[i] : 0;
  __syncthreads();
  for (int o = 128; o; o >>= 1) { if (t < o) sd[t] += sd[t+o]; __syncthreads(); }
  if (t == 0) bsum[blockIdx.x] = sd[0];
}
__global__ void scan_bsum(int* __restrict__ bsum, int nb) {
  __shared__ int sd[1024];
  int t = threadIdx.x;
  sd[t] = (t < nb) ? bsum[t] : 0;
  __syncthreads();
  for (int o = 1; o < 1024; o <<= 1) {
    int v = (t >= o) ? sd[t-o] : 0;
    __syncthreads();
    sd[t] += v;
    __syncthreads();
  }
  if (t < nb) bsum[t] = sd[t];
}
__global__ void scan_fill(const int* __restrict__ hist, const int* __restrict__ bsum,
                          int* __restrict__ roff, int* __restrict__ cursor, int N) {
  __shared__ int sd[256];
  int t = threadIdx.x;
  int i = blockIdx.x*256 + t;
  int v = (i < N) ? hist[i] : 0;
  sd[t] = v;
  __syncthreads();
  for (int o = 1; o < 256; o <<= 1) {
    int u = (t >= o) ? sd[t-o] : 0;
    __syncthreads();
    sd[t] += u;
    __syncthreads();
  }
  int boff = (blockIdx.x == 0) ? 0 : bsum[blockIdx.x - 1];
  if (i < N) {
    int excl = boff + sd[t] - v;
    roff[i] = excl;
    cursor[i] = excl;
    if (i == N - 1) roff[N] = boff + sd[t];
  }
}
__global__ void fill_all(const int* __restrict__ aa, const int* __restrict__ ab,
                         const int* __restrict__ ba,
                         int Eaa, int Eab, int Eba, int Na,
                         int* __restrict__ cursor, int* __restrict__ epack) {
  int i = blockIdx.x*blockDim.x + threadIdx.x;
  int tot = Eaa + Eab + Eba;
  if (i >= tot) return;
  int dst, slot;
  if (i < Eaa)            { dst = aa[Eaa + i];                slot = aa[i]; }
  else if (i < Eaa + Eab) { int j = i - Eaa;       dst = ab[Eab + j] + Na; slot = ab[j] + Na; }
  else                    { int j = i - Eaa - Eab; dst = ba[Eba + j];      slot = ba[j] + 2*Na; }
  int pos = atomicAdd(cursor + dst, 1);
  epack[pos] = slot;
}

// ---------- fused HGT attention, 4-way edge-parallel, depth-2 prefetch ----------
__global__ void seg_attn(const float* __restrict__ qbuf,
                         const float* __restrict__ ktv,
                         const int* __restrict__ roff, const int* __restrict__ epack,
                         float* __restrict__ agg, int Na, int N) {
  int wid = (blockIdx.x*blockDim.x + threadIdx.x) >> 6;
  int lane = threadIdx.x & 63;
  if (wid >= N) return;
  int quarter = lane >> 4;
  int u = lane & 15;
  int h = u >> 2;
  int d0 = (u & 3) * 8;
  const float* qp = qbuf + (size_t)wid*128 + h*32 + d0;
  float4 qa = *(const float4*)qp;
  float4 qb = *(const float4*)(qp + 4);
  int beg = roff[wid], end = roff[wid + 1];
  float m = -1e30f, s = 0.f;
  float4 aA = make_float4(0.f,0.f,0.f,0.f), aB = make_float4(0.f,0.f,0.f,0.f);
  int i = beg + quarter;
  float4 ka0, kb0, va0, vb0, ka1, kb1, va1, vb1;
  if (i < end) {
    const float* kp = ktv + (size_t)epack[i]*256 + h*64 + d0;
    ka0 = *(const float4*)kp;      kb0 = *(const float4*)(kp + 4);
    va0 = *(const float4*)(kp+32); vb0 = *(const float4*)(kp + 36);
  }
  if (i + 4 < end) {
    const float* kp = ktv + (size_t)epack[i+4]*256 + h*64 + d0;
    ka1 = *(const float4*)kp;      kb1 = *(const float4*)(kp + 4);
    va1 = *(const float4*)(kp+32); vb1 = *(const float4*)(kp + 36);
  }
  for (; i < end; i += 4) {
    float4 cka = ka0, ckb = kb0, cva = va0, cvb = vb0;
    ka0 = ka1; kb0 = kb1; va0 = va1; vb0 = vb1;
    int nx = i + 8;
    if (nx < end) {
      const float* kp = ktv + (size_t)epack[nx]*256 + h*64 + d0;
      ka1 = *(const float4*)kp;      kb1 = *(const float4*)(kp + 4);
      va1 = *(const float4*)(kp+32); vb1 = *(const float4*)(kp + 36);
    }
    float sc = qa.x*cka.x + qa.y*cka.y + qa.z*cka.z + qa.w*cka.w
             + qb.x*ckb.x + qb.y*ckb.y + qb.z*ckb.z + qb.w*ckb.w;
    sc += __shfl_xor(sc, 1, 64);
    sc += __shfl_xor(sc, 2, 64);
    float nm = fmaxf(m, sc);
    float scale = exp2f(m - nm);
    float e = exp2f(sc - nm);
    s = s*scale + e;
    aA.x = aA.x*scale + e*cva.x; aA.y = aA.y*scale + e*cva.y;
    aA.z = aA.z*scale + e*cva.z; aA.w = aA.w*scale + e*cva.w;
    aB.x = aB.x*scale + e*cvb.x; aB.y = aB.y*scale + e*cvb.y;
    aB.z = aB.z*scale + e*cvb.z; aB.w = aB.w*scale + e*cvb.w;
    m = nm;
  }
#pragma unroll
  for (int off = 16; off <= 32; off <<= 1) {
    float mo = __shfl_xor(m, off, 64);
    float so = __shfl_xor(s, off, 64);
    float A0 = __shfl_xor(aA.x, off, 64), A1 = __shfl_xor(aA.y, off, 64);
    float A2 = __shfl_xor(aA.z, off, 64), A3 = __shfl_xor(aA.w, off, 64);
    float B0 = __shfl_xor(aB.x, off, 64), B1 = __shfl_xor(aB.y, off, 64);
    float B2 = __shfl_xor(aB.z, off, 64), B3 = __shfl_xor(aB.w, off, 64);
    float nm = fmaxf(m, mo);
    float c1 = exp2f(m - nm), c2 = exp2f(mo - nm);
    s = s*c1 + so*c2;
    aA.x = aA.x*c1 + A0*c2; aA.y = aA.y*c1 + A1*c2;
    aA.z = aA.z*c1 + A2*c2; aA.w = aA.w*c1 + A3*c2;
    aB.x = aB.x*c1 + B0*c2; aB.y = aB.y*c1 + B1*c2;
    aB.z = aB.z*c1 + B2*c2; aB.w = aB.w*c1 + B3*c2;
    m = nm;
  }
  if (quarter == 0) {
    float inv = 1.f / (s + 1e-16f);
    float4 o1, o2;
    o1.x = aA.x*inv; o1.y = aA.y*inv; o1.z = aA.z*inv; o1.w = aA.w*inv;
    o2.x = aB.x*inv; o2.y = aB.y*inv; o2.z = aB.z*inv; o2.w = aB.w*inv;
    float* op = agg + (size_t)wid*128 + h*32 + d0;
    *(float4*)op = o1;
    *(float4*)(op + 4) = o2;
  }
}

// fused GAT scorer via CSR
__global__ void gat_all(const float* __restrict__ x1, const int* __restrict__ roff,
                        const int* __restrict__ epack,
                        const float* __restrict__ asrc, const float* __restrict__ adst,
                        int Na, int N, float* __restrict__ score) {
  int n = blockIdx.x*blockDim.x + threadIdx.x;
  if (n >= N) return;
  float xd = x1[n];
  float as_ = asrc[0], ad = adst[0];
  float e0 = xd*as_ + xd*ad;
  e0 = (e0 > 0.f) ? e0 : 0.2f*e0;
  float m = e0, s = 1.f, acc = xd;
  int beg = roff[n], end = roff[n + 1];
  for (int i = beg; i < end; i++) {
    int slot = epack[i];
    int sg = (slot < Na) ? slot : slot - Na;
    float xs = x1[sg];
    float e = xs*as_ + xd*ad;
    e = (e > 0.f) ? e : 0.2f*e;
    float nm = fmaxf(m, e);
    float sc = __expf(m - nm), ee = __expf(e - nm);
    s = s*sc + ee;  acc = acc*sc + ee*xs;  m = nm;
  }
  score[n] = acc / (s + 1e-16f);
}

// ---- parallel top-8 ----
__global__ void topk_stage1(const float* __restrict__ score, const float* __restrict__ bgat,
                            int N, float* __restrict__ cvals, int* __restrict__ cidx) {
  __shared__ float bv[256];
  __shared__ int   bi[256];
  int t = threadIdx.x;
  int chunk = (N + gridDim.x - 1) / gridDim.x;
  int i = blockIdx.x * chunk + t;
  float bg = bgat[0];
  bool valid = (t < chunk && i < N);
  float myv = valid ? score[i] + bg : -INFINITY;
  int   myi = valid ? i : 0x7FFFFFFF;
  for (int k = 0; k < 8; k++) {
    bv[t] = myv; bi[t] = myi;
    __syncthreads();
    for (int o = 128; o; o >>= 1) {
      if (t < o) {
        if (bv[t+o] > bv[t] || (bv[t+o] == bv[t] && bi[t+o] < bi[t])) { bv[t]=bv[t+o]; bi[t]=bi[t+o]; }
      }
      __syncthreads();
    }
    if (t == 0) { cvals[blockIdx.x*8 + k] = bv[0]; cidx[blockIdx.x*8 + k] = bi[0]; }
    if (myi == bi[0]) myv = -INFINITY;
    __syncthreads();
  }
}

// merged: top-8 merge + scorer-gated MLP head (single block)
__global__ void topk_mlp(const float* __restrict__ cvals, const int* __restrict__ cidx, int C,
                         const float* __restrict__ h,
                         const float* __restrict__ W1, const float* __restrict__ b1,
                         const float* __restrict__ W2, const float* __restrict__ b2,
                         const float* __restrict__ W3, const float* __restrict__ b3,
                         float* __restrict__ out) {
  __shared__ float bv[256];
  __shared__ int   bi[256];
  __shared__ int   seli[8];
  __shared__ float sval[8];
  __shared__ float hp[1024], v1[128], v2[64];
  int t = threadIdx.x;
  for (int k = 0; k < 8; k++) {
    float best = -INFINITY; int besti = 0x7FFFFFFF;
    for (int i = t; i < C; i += 256) {
      int id = cidx[i];
      bool taken = false;
      for (int j = 0; j < k; j++) if (seli[j] == id) taken = true;
      if (taken) continue;
      float v = cvals[i];
      if (v > best || (v == best && id < besti)) { best = v; besti = id; }
    }
    bv[t] = best; bi[t] = besti;
    __syncthreads();
    for (int o = 128; o; o >>= 1) {
      if (t < o) {
        if (bv[t+o] > bv[t] || (bv[t+o] == bv[t] && bi[t+o] < bi[t])) { bv[t]=bv[t+o]; bi[t]=bi[t+o]; }
      }
      __syncthreads();
    }
    if (t == 0) { seli[k] = bi[0]; sval[k] = bv[0]; }
    __syncthreads();
  }
  for (int i = t; i < 1024; i += 256) {
    int r = i >> 7, d = i & 127;
    hp[i] = h[(size_t)seli[r]*128 + d] * tanhf(sval[r]);
  }
  __syncthreads();
  if (t < 128) {
    float a = 0.f;
    for (int k = 0; k < 1024; k++) a += hp[k]*W1[(size_t)k*128 + t];
    v1[t] = gelu_f(a + b1[t]);
  }
  __syncthreads();
  if (t < 64) {
    float a = 0.f;
    for (int k = 0; k < 128; k++) a += v1[k]*W2[(size_t)k*64 + t];
    v2[t] = gelu_f(a + b2[t]);
  }
  __syncthreads();
  if (t < 16) {
    float a = 0.f;
    for (int k = 0; k < 64; k++) a += v2[k]*W3[(size_t)k*16 + t];
    float r = gelu_f(a + b3[t]);
    if (isnan(r)) r = 0.f;
    else if (isinf(r)) r = (r > 0.f) ? 3.4028234663852886e38f : -3.4028234663852886e38f;
    out[t] = r;
  }
}

extern "C" void kernel_launch(void* const* d_in, const int* in_sizes, int n_in,
                              void* d_out, int out_size, void* d_ws, size_t ws_size,
                              hipStream_t stream) {
  const float* x_a  = (const float*)d_in[0];
  const float* x_b  = (const float*)d_in[1];
  const int* ei_aa  = (const int*)d_in[2];
  const int* ei_ab  = (const int*)d_in[3];
  const int* ei_ba  = (const int*)d_in[4];
  const float* Wkqv = (const float*)d_in[5];
  const float* bkqv = (const float*)d_in[6];
  const float* Wout = (const float*)d_in[7];
  const float* bout = (const float*)d_in[8];
  const float* skip = (const float*)d_in[9];
  const float* arel = (const float*)d_in[10];
  const float* mrel = (const float*)d_in[11];
  const float* prel = (const float*)d_in[12];
  const float* ln_g = (const float*)d_in[13];
  const float* ln_b = (const float*)d_in[14];
  const float* Wgat = (const float*)d_in[15];
  const float* att_src = (const float*)d_in[16];
  const float* att_dst = (const float*)d_in[17];
  const float* bgat = (const float*)d_in[18];
  const float* W1 = (const float*)d_in[19];
  const float* b1 = (const float*)d_in[20];
  const float* W2 = (const float*)d_in[21];
  const float* b2 = (const float*)d_in[22];
  const float* W3 = (const float*)d_in[23];
  const float* b3 = (const float*)d_in[24];

  int Na = in_sizes[0]/128, Nb = in_sizes[1]/128, N = Na + Nb;
  int Eaa = in_sizes[2]/2, Eab = in_sizes[3]/2, Eba = in_sizes[4]/2;
  int Etot = Eaa + Eab + Eba;

  float* w = (float*)d_ws;
  size_t off = 0;
  auto alloc = [&](size_t n) { float* p = w + off; off += n; return p; };
  float* hbuf  = alloc((size_t)N*128);
  float* qbuf  = alloc((size_t)N*128);
  float* ktvA  = alloc((size_t)(2*Na + Nb)*256);
  float* agg   = alloc((size_t)N*128);
  float* Wc    = alloc((size_t)3*1024*128);
  float* bc    = alloc((size_t)3*1024);
  float* x1buf = alloc((size_t)N);
  float* score = alloc((size_t)N);
  float* cvals = alloc(2048);
  int*   cidx  = (int*)alloc(2048);
  int*   hist  = (int*)alloc((size_t)N);
  int*   roff  = (int*)alloc((size_t)N + 1);
  int*   cursor= (int*)alloc((size_t)N);
  int*   bsum  = (int*)alloc(1024);
  int*   epack = (int*)alloc((size_t)Etot);

  float* h_a = hbuf;
  float* h_b = hbuf + (size_t)Na*128;

  mkw<<<dim3(3*1024),dim3(128),0,stream>>>(Wkqv, bkqv, arel, mrel, prel, Wc, bc);

  int nsb = (N + 255)/256;
  hist_init<<<dim3(nsb),dim3(256),0,stream>>>(hist, N);
  hist_count_all<<<dim3((Etot+255)/256),dim3(256),0,stream>>>(ei_aa, ei_ab, ei_ba, Eaa, Eab, Eba, Na, hist);
  scan_part<<<dim3(nsb),dim3(256),0,stream>>>(hist, bsum, N);
  scan_bsum<<<dim3(1),dim3(1024),0,stream>>>(bsum, nsb);
  scan_fill<<<dim3(nsb),dim3(256),0,stream>>>(hist, bsum, roff, cursor, N);
  fill_all<<<dim3((Etot+255)/256),dim3(256),0,stream>>>(ei_aa, ei_ab, ei_ba, Eaa, Eab, Eba, Na, cursor, epack);

  int nba = (Na + 127)/128, nbb = (Nb + 127)/128;
  int fba = (Na + 63)/64, fbb = (Nb + 63)/64;   // finish_tile: 64-row tiles

  for (int L = 0; L < 3; L++) {
    const float* xa_in = (L == 0) ? x_a : h_a;
    const float* xb_in = (L == 0) ? x_b : h_b;
    const float* WcA = Wc + (size_t)L*1024*128;
    const float* WcB = WcA + (size_t)640*128;
    const float* bcA = bc + (size_t)L*1024;
    const float* bcB = bcA + 640;
    gemm_tile2<<<dim3(nba*5 + nbb*3),dim3(256),0,stream>>>(xa_in, xb_in, WcA, WcB, bcA, bcB,
                                                           qbuf, ktvA, Na, Nb, nba, nbb);
    seg_attn<<<dim3((N+3)/4),dim3(256),0,stream>>>(qbuf, ktvA, roff, epack, agg, Na, N);
    int mode = (L == 0) ? 0 : (L == 2 ? 2 : 1);
    finish_tile<<<dim3(fba + fbb),dim3(256),0,stream>>>(agg, xa_in, xb_in, h_a, h_b,
                                                        Wout + (size_t)L*2*16384,
                                                        bout + (size_t)L*2*128,
                                                        skip + L*2, ln_g, ln_b,
                                                        Wgat, x1buf, mode, Na, Nb);
  }

  gat_all<<<dim3((N+255)/256),dim3(256),0,stream>>>(x1buf, roff, epack, att_src, att_dst, Na, N, score);
  int tk_blocks = (N + 255)/256;
  topk_stage1<<<dim3(tk_blocks),dim3(256),0,stream>>>(score, bgat, N, cvals, cidx);
  topk_mlp<<<dim3(1),dim3(256),0,stream>>>(cvals, cidx, tk_blocks*8, hbuf,
                                           W1, b1, W2, b2, W3, b3, (float*)d_out);
}